// Round 5
// baseline (1116.331 us; speedup 1.0000x reference)
//
#include <hip/hip_runtime.h>
#include <hip/hip_cooperative_groups.h>

namespace cg = cooperative_groups;

typedef __attribute__((ext_vector_type(8))) short short8;
typedef __attribute__((ext_vector_type(4))) float float4v;
typedef __attribute__((ext_vector_type(4))) unsigned short ushort4v;

#define DEV __device__ __forceinline__
#define AGENT __HIP_MEMORY_SCOPE_AGENT

DEV unsigned short f2bf(float f) {
  union { float f; unsigned u; } v; v.f = f;
  unsigned r = v.u + 0x7fffu + ((v.u >> 16) & 1u);
  return (unsigned short)(r >> 16);
}
DEV float bf2f(unsigned short h) {
  union { unsigned u; float f; } v; v.u = ((unsigned)h) << 16;
  return v.f;
}
DEV unsigned pk2(float a, float b) {
  return (unsigned)f2bf(a) | ((unsigned)f2bf(b) << 16);
}

// async global->LDS, 16B per lane; LDS dest is wave-uniform base + lane*16
DEV void gl2lds16(const void* g, void* l) {
  __builtin_amdgcn_global_load_lds(
      (const __attribute__((address_space(1))) void*)g,
      (__attribute__((address_space(3))) void*)l, 16, 0, 0);
}

// --- cross-workgroup data movement: LLC write-through / bypass ------------
DEV void ast32(unsigned short* p, unsigned v) {
  __hip_atomic_store((unsigned*)p, v, __ATOMIC_RELAXED, AGENT);
}
DEV short8 ald16(const unsigned short* p) {
  unsigned long long lo = __hip_atomic_load((const unsigned long long*)p,     __ATOMIC_RELAXED, AGENT);
  unsigned long long hi = __hip_atomic_load((const unsigned long long*)p + 1, __ATOMIC_RELAXED, AGENT);
  union { unsigned long long q[2]; short8 s; } u;
  u.q[0] = lo; u.q[1] = hi;
  return u.s;
}

// Grid barrier (verbatim R3, proven): wg stores flags[wg]=epoch (own line);
// wave0's 64 lanes each poll one wg's flag, __all across the wave.
// Leading __syncthreads drains vmcnt (publish stores at LLC) before the flag.
DEV void bar(unsigned* flags, unsigned epoch) {
  __syncthreads();
  if (threadIdx.x < 64) {
    const int lane = threadIdx.x;
    if (lane == 0)
      __hip_atomic_store(&flags[blockIdx.x * 32], epoch, __ATOMIC_RELAXED, AGENT);
    bool ok = false;
    do {
      ok = ok || (__hip_atomic_load(&flags[lane * 32], __ATOMIC_RELAXED, AGENT) >= epoch);
    } while (!__all(ok));
  }
  __syncthreads();
}

__global__ __launch_bounds__(256) void zero_flags(unsigned* p, int n) {
  int i = blockIdx.x * 256 + threadIdx.x;
  if (i < n) p[i] = 0;
}

// ---------------------------------------------------------------------------
// fp32 -> bf16 convert, 4 elems/thread
__global__ __launch_bounds__(256) void cvt4(const float* __restrict__ in,
                                            unsigned short* __restrict__ out, int n4) {
  const int idx = blockIdx.x * 256 + threadIdx.x;
  if (idx >= n4) return;
  float4 v = ((const float4*)in)[idx];
  ushort4v o = { f2bf(v.x), f2bf(v.y), f2bf(v.z), f2bf(v.w) };
  ((ushort4v*)out)[idx] = o;
}

// ---------------------------------------------------------------------------
// Gather X[row] = [emb(kw_{i+1}) | emb(lw_i)] as bf16, row = i*32+b
__global__ __launch_bounds__(256) void gatherx(const float* __restrict__ emb,
                                               const int* __restrict__ targets,
                                               const int* __restrict__ tkws,
                                               unsigned short* __restrict__ X) {
  const int row = blockIdx.x;
  const int i = row >> 5, b = row & 31;
  const int t = threadIdx.x;
  const int kw = tkws[b * 64 + i + 1];
  const int lw = targets[b * 64 + i];
  const float4* src = (t < 128) ? (const float4*)(emb + (size_t)kw * 512)
                                : (const float4*)(emb + (size_t)lw * 512);
  const int c = t & 127;
  float4 v = src[c];
  ushort4v o = { f2bf(v.x), f2bf(v.y), f2bf(v.z), f2bf(v.w) };
  ((ushort4v*)(X + (size_t)row * 1024))[(t < 128 ? 0 : 128) + c] = o;
}

// ---------------------------------------------------------------------------
// C = A[M,1024] * B[N,1024]^T, 128x128 tile, BK=32, bf16 MFMA 16x16x32.
// EPI=0: store fp32 C (ldc = ldc_or_nvt).
// EPI=1: add bias, per-row (max, sum-exp) over this 128-col tile -> partials.
template <int EPI>
__global__ __launch_bounds__(256, 1) void gemm_bt(
    const unsigned short* __restrict__ A,
    const unsigned short* __restrict__ B,
    float* __restrict__ out,
    const float* __restrict__ bias,
    int ldc_or_nvt) {
  __shared__ __align__(16) unsigned short As[128 * 32];
  __shared__ __align__(16) unsigned short Bs[128 * 32];
  __shared__ float ms[2][128][2];
  const int tid = threadIdx.x;
  const int w = tid >> 6, lane = tid & 63;
  const int r4 = lane >> 2, c4 = lane & 3;
  const int m0 = blockIdx.x * 128, n0 = blockIdx.y * 128;
  const int m_off = (w & 1) * 64, n_off = (w >> 1) * 64;
  const int lrow = lane & 15, lk = (lane >> 4) * 8;

  const unsigned short* Ab = A + (size_t)(m0 + w * 16 + r4) * 1024 + c4 * 8;
  const unsigned short* Bb = B + (size_t)(n0 + w * 16 + r4) * 1024 + c4 * 8;

  float4v acc[4][4] = {};

  for (int k0 = 0; k0 < 1024; k0 += 32) {
    gl2lds16(Ab + k0,             &As[w * 512]);
    gl2lds16(Ab + 64 * 1024 + k0, &As[2048 + w * 512]);
    gl2lds16(Bb + k0,             &Bs[w * 512]);
    gl2lds16(Bb + 64 * 1024 + k0, &Bs[2048 + w * 512]);
    __syncthreads();
    short8 af[4], bfr[4];
#pragma unroll
    for (int t = 0; t < 4; t++) {
      af[t]  = *(const short8*)&As[(m_off + t * 16 + lrow) * 32 + lk];
      bfr[t] = *(const short8*)&Bs[(n_off + t * 16 + lrow) * 32 + lk];
    }
#pragma unroll
    for (int mt = 0; mt < 4; mt++)
#pragma unroll
      for (int nt = 0; nt < 4; nt++)
        acc[mt][nt] = __builtin_amdgcn_mfma_f32_16x16x32_bf16(af[mt], bfr[nt], acc[mt][nt], 0, 0, 0);
    __syncthreads();
  }

  if constexpr (EPI == 0) {
    const int ldc = ldc_or_nvt;
#pragma unroll
    for (int mt = 0; mt < 4; mt++) {
      const int gr = m0 + m_off + mt * 16 + (lane >> 4) * 4;
#pragma unroll
      for (int nt = 0; nt < 4; nt++) {
        const int gc = n0 + n_off + nt * 16 + lrow;
#pragma unroll
        for (int rg = 0; rg < 4; rg++)
          out[(size_t)(gr + rg) * ldc + gc] = acc[mt][nt][rg];
      }
    }
  } else {
    const int nvt = ldc_or_nvt;
    float b4[4];
#pragma unroll
    for (int nt = 0; nt < 4; nt++) b4[nt] = bias[n0 + n_off + nt * 16 + lrow];
#pragma unroll
    for (int mt = 0; mt < 4; mt++) {
#pragma unroll
      for (int rg = 0; rg < 4; rg++) {
        float v0 = acc[mt][0][rg] + b4[0];
        float v1 = acc[mt][1][rg] + b4[1];
        float v2 = acc[mt][2][rg] + b4[2];
        float v3 = acc[mt][3][rg] + b4[3];
        float mx = fmaxf(fmaxf(v0, v1), fmaxf(v2, v3));
#pragma unroll
        for (int d = 1; d < 16; d <<= 1) mx = fmaxf(mx, __shfl_xor(mx, d, 64));
        float s = __expf(v0 - mx) + __expf(v1 - mx) + __expf(v2 - mx) + __expf(v3 - mx);
#pragma unroll
        for (int d = 1; d < 16; d <<= 1) s += __shfl_xor(s, d, 64);
        if ((lane & 15) == 0) {
          int r = m_off + mt * 16 + (lane >> 4) * 4 + rg;
          ms[w >> 1][r][0] = mx;
          ms[w >> 1][r][1] = s;
        }
      }
    }
    __syncthreads();
    if (tid < 128) {
      float m1 = ms[0][tid][0], s1 = ms[0][tid][1];
      float m2 = ms[1][tid][0], s2 = ms[1][tid][1];
      float M = fmaxf(m1, m2);
      float S = s1 * __expf(m1 - M) + s2 * __expf(m2 - M);
      ((float2*)out)[(size_t)(m0 + tid) * nvt + blockIdx.y] = make_float2(M, S);
    }
  }
}

// ---------------------------------------------------------------------------
// Cooperative recurrence, flipped operands: D = Whh_slice @ h^T.
// 64 wgs x 128 thr (2 waves). wg owns 16 j-cols; wave wv owns batches
// wv*16..wv*16+15. Lane holds (j = jb + quad*4 + rg, b = wv*16 + (lane&15))
// for acc, gates, h_old, sent_old, Gi, biases and the publish stores --
// zero block-level reductions, one barrier per hot step. Whh slice lives in
// LDS as exact per-lane fragments [ks*3+g][lane]x16B (96 KB, wave-linear
// conflict-free ds_read_b128).
__global__ __launch_bounds__(128, 1) void recur_kernel(
    const float* __restrict__ Gi,
    const unsigned short* __restrict__ WhhB,
    const unsigned short* __restrict__ sWihB,
    const unsigned short* __restrict__ sWhhB,
    unsigned short* __restrict__ h_pub,      // 2 x 32768 u16
    unsigned short* __restrict__ sent_pub,   // 2 x 32768 u16
    unsigned short* __restrict__ WH,
    const float* __restrict__ w_bih, const float* __restrict__ w_bhh,
    const float* __restrict__ s_bih, const float* __restrict__ s_bhh,
    const int* __restrict__ targets,
    const float* __restrict__ sent_state,
    unsigned* __restrict__ flags) {
  __shared__ __align__(16) unsigned short Afrag[96 * 64 * 8];   // 96 KB
  const int tid = threadIdx.x;
  const int wv = tid >> 6, lane = tid & 63;
  const int lr = lane & 15, q = lane >> 4;
  const int jb = blockIdx.x * 16;
  const int b  = wv * 16 + lr;               // this lane's batch
  const int jq = jb + q * 4;                 // this lane's first j
  unsigned epoch = 0;
  int scur = 0;

  // ---- one-time: Whh wg-slice -> LDS as per-lane MFMA A-fragments ----
  // Afrag[(ks*3+g)*64 + l] holds Whh[g*1024 + jb + (l&15)][ks*32 + (l>>4)*8 ..+7]
  for (int s = tid; s < 96 * 64; s += 128) {
    const int ksg = s >> 6, l = s & 63;
    const int ks = ksg / 3, g = ksg - ks * 3;
    const int m = l & 15, kq = l >> 4;
    short8 v = *(const short8*)&WhhB[((size_t)(g * 1024 + jb + m)) * 1024 + ks * 32 + kq * 8];
    *(short8*)&Afrag[(size_t)s * 8] = v;
  }

  // ---- one-time: per-step "any EOS" bitmask (grid-uniform) ----
  unsigned long long eosmask;
  {
    bool e = false;
    if (lane < 63)
      for (int bb = 0; bb < 32; bb++) e |= (targets[bb * 64 + lane + 1] == 1);
    eosmask = __ballot(e);
  }

  // ---- one-time: biases (float4 per gate, j = jq..jq+3) ----
  float4 bi[3], bh[3];
#pragma unroll
  for (int g = 0; g < 3; g++) {
    bi[g] = *(const float4*)&w_bih[g * 1024 + jq];
    bh[g] = *(const float4*)&w_bhh[g * 1024 + jq];
  }

  // ---- init state in registers, publish to parity 0 ----
  float4 h_old = *(const float4*)&sent_state[b * 1024 + jq];
  float4 s_old = h_old;
  ast32(&h_pub[b * 1024 + jq],        pk2(h_old.x, h_old.y));
  ast32(&h_pub[b * 1024 + jq + 2],    pk2(h_old.z, h_old.w));
  ast32(&sent_pub[b * 1024 + jq],     pk2(s_old.x, s_old.y));
  ast32(&sent_pub[b * 1024 + jq + 2], pk2(s_old.z, s_old.w));

  // ---- Gi prefetch for step 0 ----
  float4 gi[3];
#pragma unroll
  for (int g = 0; g < 3; g++) gi[g] = *(const float4*)&Gi[(size_t)b * 3072 + g * 1024 + jq];

  epoch++; bar(flags, epoch);

  for (int i = 0; i < 63; i++) {
    const unsigned short* hr = h_pub + (i & 1) * 32768;
    const bool anyeos = (eosmask >> i) & 1;

    // gh^T = Whh_slice @ h^T : A from LDS frags, B(h) from LLC
    float4v acc[3] = {};
#pragma unroll
    for (int ks = 0; ks < 32; ks++) {
      short8 bfr = ald16(&hr[b * 1024 + ks * 32 + q * 8]);
#pragma unroll
      for (int g = 0; g < 3; g++) {
        short8 afr = *(const short8*)&Afrag[(size_t)((ks * 3 + g) * 64 + lane) * 8];
        acc[g] = __builtin_amdgcn_mfma_f32_16x16x32_bf16(afr, bfr, acc[g], 0, 0, 0);
      }
    }

    // gates, fully in-lane
    float wh[4];
#pragma unroll
    for (int rg = 0; rg < 4; rg++) {
      float ghr = acc[0][rg] + ((const float*)&bh[0])[rg];
      float ghz = acc[1][rg] + ((const float*)&bh[1])[rg];
      float ghn = acc[2][rg] + ((const float*)&bh[2])[rg];
      float gir = ((const float*)&gi[0])[rg] + ((const float*)&bi[0])[rg];
      float giz = ((const float*)&gi[1])[rg] + ((const float*)&bi[1])[rg];
      float gin = ((const float*)&gi[2])[rg] + ((const float*)&bi[2])[rg];
      float r = 1.f / (1.f + __expf(-(gir + ghr)));
      float z = 1.f / (1.f + __expf(-(giz + ghz)));
      float n = tanhf(gin + r * ghn);
      wh[rg] = (1.f - z) * n + z * ((const float*)&h_old)[rg];
    }
    const unsigned pw01 = pk2(wh[0], wh[1]);
    const unsigned pw23 = pk2(wh[2], wh[3]);
    ast32(&WH[(size_t)(i * 32 + b) * 1024 + jq],     pw01);
    ast32(&WH[(size_t)(i * 32 + b) * 1024 + jq + 2], pw23);

    // Gi prefetch for next step (barrier-independent)
    if (i < 62) {
#pragma unroll
      for (int g = 0; g < 3; g++)
        gi[g] = *(const float4*)&Gi[(size_t)((i + 1) * 32 + b) * 3072 + g * 1024 + jq];
    }

    if (!anyeos) {
      h_old.x = wh[0]; h_old.y = wh[1]; h_old.z = wh[2]; h_old.w = wh[3];
      ast32(&h_pub[((i + 1) & 1) * 32768 + b * 1024 + jq],     pw01);
      ast32(&h_pub[((i + 1) & 1) * 32768 + b * 1024 + jq + 2], pw23);
      epoch++; bar(flags, epoch);
    } else {
      // --- cold path (EOS in some batch this step) ---
      epoch++; bar(flags, epoch);   // WH[i] visible grid-wide
      // gi_s^T = sWih_slice @ wh^T   (A straight from global)
      float4v a2[3] = {};
#pragma unroll
      for (int ks = 0; ks < 32; ks++) {
        short8 bfr = ald16(&WH[(size_t)(i * 32 + b) * 1024 + ks * 32 + q * 8]);
#pragma unroll
        for (int g = 0; g < 3; g++) {
          short8 afr = *(const short8*)&sWihB[((size_t)(g * 1024 + jb + lr)) * 1024 + ks * 32 + q * 8];
          a2[g] = __builtin_amdgcn_mfma_f32_16x16x32_bf16(afr, bfr, a2[g], 0, 0, 0);
        }
      }
      // gh_s^T = sWhh_slice @ sent^T
      const unsigned short* sr = sent_pub + scur * 32768;
      float4v a3[3] = {};
#pragma unroll
      for (int ks = 0; ks < 32; ks++) {
        short8 bfr = ald16(&sr[b * 1024 + ks * 32 + q * 8]);
#pragma unroll
        for (int g = 0; g < 3; g++) {
          short8 afr = *(const short8*)&sWhhB[((size_t)(g * 1024 + jb + lr)) * 1024 + ks * 32 + q * 8];
          a3[g] = __builtin_amdgcn_mfma_f32_16x16x32_bf16(afr, bfr, a3[g], 0, 0, 0);
        }
      }
      float4 sbi[3], sbh[3];
#pragma unroll
      for (int g = 0; g < 3; g++) {
        sbi[g] = *(const float4*)&s_bih[g * 1024 + jq];
        sbh[g] = *(const float4*)&s_bhh[g * 1024 + jq];
      }
      const bool m = (targets[b * 64 + i + 1] == 1);
      float nh[4], ns[4];
#pragma unroll
      for (int rg = 0; rg < 4; rg++) {
        float gr_ = a2[0][rg] + ((const float*)&sbi[0])[rg] + a3[0][rg] + ((const float*)&sbh[0])[rg];
        float gz_ = a2[1][rg] + ((const float*)&sbi[1])[rg] + a3[1][rg] + ((const float*)&sbh[1])[rg];
        float r = 1.f / (1.f + __expf(-gr_));
        float z = 1.f / (1.f + __expf(-gz_));
        float n = tanhf(a2[2][rg] + ((const float*)&sbi[2])[rg] +
                        r * (a3[2][rg] + ((const float*)&sbh[2])[rg]));
        float so = ((const float*)&s_old)[rg];
        float tmp = (1.f - z) * n + z * so;
        ns[rg] = m ? tmp : so;
        nh[rg] = m ? tmp : wh[rg];
      }
      s_old.x = ns[0]; s_old.y = ns[1]; s_old.z = ns[2]; s_old.w = ns[3];
      h_old.x = nh[0]; h_old.y = nh[1]; h_old.z = nh[2]; h_old.w = nh[3];
      ast32(&sent_pub[(scur ^ 1) * 32768 + b * 1024 + jq],     pk2(ns[0], ns[1]));
      ast32(&sent_pub[(scur ^ 1) * 32768 + b * 1024 + jq + 2], pk2(ns[2], ns[3]));
      ast32(&h_pub[((i + 1) & 1) * 32768 + b * 1024 + jq],     pk2(nh[0], nh[1]));
      ast32(&h_pub[((i + 1) & 1) * 32768 + b * 1024 + jq + 2], pk2(nh[2], nh[3]));
      scur ^= 1;
      epoch++; bar(flags, epoch);
    }
  }
}

// ---------------------------------------------------------------------------
// Per row: y = WH[row].outW[tgt] + out_b[tgt]; lse from 250 (m,s) partials;
// term = valid * (y - lse). One wave per row.
__global__ __launch_bounds__(256) void row_loss(
    const unsigned short* __restrict__ WH,
    const unsigned short* __restrict__ outWb,
    const float* __restrict__ out_b,
    const int* __restrict__ targets,
    const int* __restrict__ targets_len,
    const float2* __restrict__ partials,
    float* __restrict__ term) {
  const int wv = threadIdx.x >> 6, lane = threadIdx.x & 63;
  const int row = blockIdx.x * 4 + wv;
  const int b = row & 31, i = row >> 5;
  const int tgt = targets[b * 64 + i + 1];
  const short8* a8 = (const short8*)(WH + (size_t)row * 1024);
  const short8* w8 = (const short8*)(outWb + (size_t)tgt * 1024);
  float s = 0.f;
#pragma unroll
  for (int c = 0; c < 2; c++) {
    short8 av = a8[lane + 64 * c];
    short8 wv8 = w8[lane + 64 * c];
#pragma unroll
    for (int j = 0; j < 8; j++)
      s += bf2f((unsigned short)av[j]) * bf2f((unsigned short)wv8[j]);
  }
#pragma unroll
  for (int d = 32; d; d >>= 1) s += __shfl_xor(s, d, 64);

  float m = -1e30f, ssum = 0.f;
  for (int vt = lane; vt < 250; vt += 64) {
    float2 pp = partials[(size_t)row * 250 + vt];
    float nm = fmaxf(m, pp.x);
    ssum = ssum * __expf(m - nm) + pp.y * __expf(pp.x - nm);
    m = nm;
  }
#pragma unroll
  for (int d = 32; d; d >>= 1) {
    float om = __shfl_xor(m, d, 64);
    float os = __shfl_xor(ssum, d, 64);
    float nm = fmaxf(m, om);
    ssum = ssum * __expf(m - nm) + os * __expf(om - nm);
    m = nm;
  }
  if (lane == 0) {
    float y = s + out_b[tgt];
    float lse = m + logf(ssum);
    float valid = (targets_len[b] > i + 1) ? 1.f : 0.f;
    term[row] = valid * (y - lse);
  }
}

__global__ void final_sum(const float* __restrict__ term, float* __restrict__ out) {
  __shared__ float red[256];
  float s = 0.f;
  for (int r = threadIdx.x; r < 2016; r += 256) s += term[r];
  red[threadIdx.x] = s;
  __syncthreads();
  for (int st = 128; st; st >>= 1) {
    if ((int)threadIdx.x < st) red[threadIdx.x] += red[threadIdx.x + st];
    __syncthreads();
  }
  if (threadIdx.x == 0) out[0] = -red[0];
}

// ---------------------------------------------------------------------------
extern "C" void kernel_launch(void* const* d_in, const int* in_sizes, int n_in,
                              void* d_out, int out_size, void* d_ws, size_t ws_size,
                              hipStream_t stream) {
  const int*   targets     = (const int*)d_in[0];
  const int*   targets_kws = (const int*)d_in[1];
  const float* sent_state  = (const float*)d_in[2];
  const int*   targets_len = (const int*)d_in[3];
  const float* emb_W       = (const float*)d_in[4];
  const float* w_Wih       = (const float*)d_in[5];
  const float* w_Whh       = (const float*)d_in[6];
  const float* w_bih       = (const float*)d_in[7];
  const float* w_bhh       = (const float*)d_in[8];
  const float* s_Wih       = (const float*)d_in[9];
  const float* s_Whh       = (const float*)d_in[10];
  const float* s_bih       = (const float*)d_in[11];
  const float* s_bhh       = (const float*)d_in[12];
  const float* out_W       = (const float*)d_in[13];
  const float* out_b       = (const float*)d_in[14];

  char* base = (char*)d_ws;
  size_t off = 0;
  auto alloc = [&](size_t bytes) -> void* {
    void* r = base + off;
    off += (bytes + 255) & ~(size_t)255;
    return r;
  };
  unsigned short* outWb   = (unsigned short*)alloc(32000ull * 1024 * 2);
  unsigned short* WihB    = (unsigned short*)alloc(3072ull * 1024 * 2);
  unsigned short* WhhB    = (unsigned short*)alloc(3072ull * 1024 * 2);
  unsigned short* sWihB   = (unsigned short*)alloc(3072ull * 1024 * 2);
  unsigned short* sWhhB   = (unsigned short*)alloc(3072ull * 1024 * 2);
  unsigned short* Xb      = (unsigned short*)alloc(2048ull * 1024 * 2);
  float*          Gi      = (float*)alloc(2048ull * 3072 * 4);
  unsigned short* WH      = (unsigned short*)alloc(2048ull * 1024 * 2);
  unsigned short* h_pub   = (unsigned short*)alloc(2 * 32ull * 1024 * 2);
  unsigned short* sent_pub= (unsigned short*)alloc(2 * 32ull * 1024 * 2);
  float2*         parts   = (float2*)alloc(2048ull * 250 * 8);
  float*          term    = (float*)alloc(2048ull * 4);
  unsigned*       flags   = (unsigned*)alloc(64 * 32 * 4);

  zero_flags<<<8, 256, 0, stream>>>(flags, 2048);
  cvt4<<<32000, 256, 0, stream>>>(out_W, outWb, 8192000);
  cvt4<<<3072, 256, 0, stream>>>(w_Wih, WihB, 786432);
  cvt4<<<3072, 256, 0, stream>>>(w_Whh, WhhB, 786432);
  cvt4<<<3072, 256, 0, stream>>>(s_Wih, sWihB, 786432);
  cvt4<<<3072, 256, 0, stream>>>(s_Whh, sWhhB, 786432);
  gatherx<<<2016, 256, 0, stream>>>(emb_W, targets, targets_kws, Xb);
  gemm_bt<0><<<dim3(16, 24), 256, 0, stream>>>(Xb, WihB, Gi, nullptr, 3072);

  void* kargs[] = { (void*)&Gi, (void*)&WhhB, (void*)&sWihB, (void*)&sWhhB,
                    (void*)&h_pub, (void*)&sent_pub, (void*)&WH,
                    (void*)&w_bih, (void*)&w_bhh, (void*)&s_bih, (void*)&s_bhh,
                    (void*)&targets, (void*)&sent_state, (void*)&flags };
  hipLaunchCooperativeKernel((void*)recur_kernel, dim3(64), dim3(128), kargs, 0, stream);

  gemm_bt<1><<<dim3(16, 250), 256, 0, stream>>>(WH, outWb, (float*)parts, out_b, 250);
  row_loss<<<504, 256, 0, stream>>>(WH, outWb, out_b, targets, targets_len, parts, term);
  final_sum<<<1, 256, 0, stream>>>(term, (float*)d_out);
}